// Round 1
// baseline (248.608 us; speedup 1.0000x reference)
//
#include <hip/hip_runtime.h>
#include <math.h>

#define T_DIM 64
#define U_DIM 142
#define I_DIM 4500
#define B_DIM 16384
#define K_TOP 10

// One wave (64 lanes) per batch element.
// Lane v owns users {v, v+64, v+128}. Top-10 via iterative max-extraction:
// 3-way local argmax + 6-step __shfl_xor butterfly carrying (val, contrib, idx).
// Ties broken toward lower user index (only exact ties are sim==0, whose
// contribution is exactly 0, so tie choice cannot affect the output).
__global__ __launch_bounds__(256) void ucf_kernel(
    const float* __restrict__ qos,       // [T,U,I]
    const float* __restrict__ user_avg,  // [T,U]
    const float* __restrict__ user_sim,  // [U,U]
    const int*   __restrict__ user_id,   // [B]
    const int*   __restrict__ item_id,   // [B]
    const int*   __restrict__ time_id,   // [B]
    float*       __restrict__ out)       // [B]
{
    const int lane = threadIdx.x & 63;
    const int wid  = threadIdx.x >> 6;
    const int b    = blockIdx.x * 4 + wid;
    if (b >= B_DIM) return;

    const int u = user_id[b];
    const int i = item_id[b];
    const int t = time_id[b];

    const float* qcol = qos + ((size_t)t * U_DIM) * (size_t)I_DIM + i; // qcol[v*I]
    const float* srow = user_sim + (size_t)u * U_DIM;
    const float* arow = user_avg + (size_t)t * U_DIM;

    // Load candidates: sim value (masked by rated) and its contribution term.
    float val[3];
    float con[3];
#pragma unroll
    for (int j = 0; j < 3; ++j) {
        const int v = lane + j * 64;
        float sv = -INFINITY;   // out-of-range users never selected
        float cv = 0.0f;
        if (v < U_DIM) {
            const float rv = qcol[(size_t)v * I_DIM];  // scattered, stride 18 KB
            const float av = arow[v];                  // coalesced, hot in L1
            const float s  = srow[v];                  // coalesced, hot in L1
            sv = (rv > 0.0f) ? s : 0.0f;               // sim_m
            cv = sv * (rv - av);                       // sim * (r_v - avg_v)
        }
        val[j] = sv;
        con[j] = cv;
    }

    float ssum = 0.0f;  // sum of top-k sims
    float wsum = 0.0f;  // sum of top-k sim*(r-avg)
#pragma unroll
    for (int k = 0; k < K_TOP; ++k) {
        // local argmax over the 3 slots (ascending v, strict > keeps lower v on tie)
        float mv = val[0]; float mc = con[0]; int mk = lane;
        if (val[1] > mv) { mv = val[1]; mc = con[1]; mk = lane + 64; }
        if (val[2] > mv) { mv = val[2]; mc = con[2]; mk = lane + 128; }
        // wave butterfly max-reduce, tie -> lower user index (deterministic,
        // all lanes converge to identical (mv, mc, mk))
#pragma unroll
        for (int off = 32; off > 0; off >>= 1) {
            const float ov = __shfl_xor(mv, off, 64);
            const float oc = __shfl_xor(mc, off, 64);
            const int   ok = __shfl_xor(mk, off, 64);
            if (ov > mv || (ov == mv && ok < mk)) { mv = ov; mc = oc; mk = ok; }
        }
        ssum += mv;
        wsum += mc;
        // winner's owner lane removes it from candidacy
        if ((mk & 63) == lane) {
            const int slot = mk >> 6;
            if (slot == 0)      val[0] = -INFINITY;
            else if (slot == 1) val[1] = -INFINITY;
            else                val[2] = -INFINITY;
        }
    }

    if (lane == 0) {
        const float avg_u = arow[u];
        // top_sim/(sum+1e-8) then dot == wsum/(ssum+1e-8)
        out[b] = avg_u + wsum / (ssum + 1e-8f);
    }
}

extern "C" void kernel_launch(void* const* d_in, const int* in_sizes, int n_in,
                              void* d_out, int out_size, void* d_ws, size_t ws_size,
                              hipStream_t stream) {
    const float* qos  = (const float*)d_in[0];
    const float* uavg = (const float*)d_in[1];
    const float* usim = (const float*)d_in[2];
    const int*   uid  = (const int*)d_in[3];
    const int*   iid  = (const int*)d_in[4];
    const int*   tid  = (const int*)d_in[5];
    // d_in[6] is top_k, fixed at 10 by the problem instance (K_TOP).
    float* out = (float*)d_out;

    dim3 block(256);                 // 4 waves/block
    dim3 grid(B_DIM / 4);            // 16384 waves total, one per batch element
    ucf_kernel<<<grid, block, 0, stream>>>(qos, uavg, usim, uid, iid, tid, out);
}